// Round 1
// baseline (96.783 us; speedup 1.0000x reference)
//
#include <hip/hip_runtime.h>
#include <hip/hip_bf16.h>

// Reference reduces exactly to: out = x @ W^T + bias  (see round-0 analysis:
// G_pos - G_neg = G_eff, and k_G/k_I cancel). Plain linear layer,
// M=512, N=2048, K=2048, fp32 in/out. Computed in bf16 MFMA, fp32 accum.

typedef float  float4_t __attribute__((ext_vector_type(4)));
typedef short  short8_t __attribute__((ext_vector_type(8)));
typedef float  floatx4  __attribute__((ext_vector_type(4)));

constexpr int M = 512, N = 2048, K = 2048;
constexpr int BM = 64, BN = 64, BK = 64;
constexpr int LDK = BK + 8;   // bf16 elems; +16B pad keeps 16B align, spreads banks

__global__ __launch_bounds__(256)
void memristor_gemm(const float* __restrict__ x, const float* __restrict__ w,
                    const float* __restrict__ bias, float* __restrict__ out)
{
    __shared__ __hip_bfloat16 As[BM][LDK];
    __shared__ __hip_bfloat16 Bs[BN][LDK];

    const int tid  = threadIdx.x;
    const int bn   = blockIdx.x;          // N/BN = 32
    const int bm   = blockIdx.y;          // M/BM = 8
    const int lane = tid & 63;
    const int wave = tid >> 6;            // 0..3 (2x2 wave grid)
    const int wm   = (wave >> 1) * 32;    // wave row offset in tile
    const int wn   = (wave & 1) * 32;     // wave col offset in tile
    const int l16  = lane & 15;
    const int quad = lane >> 4;           // 0..3

    floatx4 acc[2][2];
    #pragma unroll
    for (int i = 0; i < 2; ++i)
        #pragma unroll
        for (int j = 0; j < 2; ++j)
            acc[i][j] = (floatx4){0.f, 0.f, 0.f, 0.f};

    // Staging layout: 64x64 fp32 tile = 1024 float4; 256 threads x 4 passes.
    // Pass p: flat = p*256 + tid; row = flat>>4 (= p*16 + tid>>4), col4 = flat&15.
    const int sr = tid >> 4;              // 0..15
    const int sc = (tid & 15) << 2;       // 0,4,...,60  (fp32 elems)

    const float* xrow = x + (size_t)(bm * BM + sr) * K + sc;
    const float* wrow = w + (size_t)(bn * BN + sr) * K + sc;

    for (int k0 = 0; k0 < K; k0 += BK) {
        // ---- stage A,B tiles: coalesced float4 global loads, cvt to bf16, ds_write 8B
        float4_t va[4], vb[4];
        #pragma unroll
        for (int p = 0; p < 4; ++p) {
            va[p] = *(const float4_t*)(xrow + (size_t)(p * 16) * K + k0);
            vb[p] = *(const float4_t*)(wrow + (size_t)(p * 16) * K + k0);
        }
        #pragma unroll
        for (int p = 0; p < 4; ++p) {
            const int r = p * 16 + sr;
            union { __hip_bfloat16 h[4]; unsigned long long u; } ua, ub;
            ua.h[0] = __float2bfloat16(va[p].x);
            ua.h[1] = __float2bfloat16(va[p].y);
            ua.h[2] = __float2bfloat16(va[p].z);
            ua.h[3] = __float2bfloat16(va[p].w);
            ub.h[0] = __float2bfloat16(vb[p].x);
            ub.h[1] = __float2bfloat16(vb[p].y);
            ub.h[2] = __float2bfloat16(vb[p].z);
            ub.h[3] = __float2bfloat16(vb[p].w);
            *(unsigned long long*)&As[r][sc] = ua.u;
            *(unsigned long long*)&Bs[r][sc] = ub.u;
        }
        __syncthreads();

        // ---- compute: 2 k-steps of 16x16x32, 2x2 MFMA tiles per wave
        #pragma unroll
        for (int kk = 0; kk < BK; kk += 32) {
            short8_t af[2], bf[2];
            #pragma unroll
            for (int t = 0; t < 2; ++t) {
                // A-operand: A[m = lane&15][k = quad*8 + j], contiguous 16B
                af[t] = *(const short8_t*)(&As[wm + t * 16 + l16][kk + quad * 8]);
                // B^T-operand from N-major storage: B[n = lane&15][k = quad*8 + j]
                bf[t] = *(const short8_t*)(&Bs[wn + t * 16 + l16][kk + quad * 8]);
            }
            #pragma unroll
            for (int i = 0; i < 2; ++i)
                #pragma unroll
                for (int j = 0; j < 2; ++j)
                    acc[i][j] = __builtin_amdgcn_mfma_f32_16x16x32_bf16(
                        af[i], bf[j], acc[i][j], 0, 0, 0);
        }
        __syncthreads();
    }

    // ---- epilogue: C/D layout col = lane&15, row = quad*4 + reg
    #pragma unroll
    for (int j = 0; j < 2; ++j) {
        const int col = bn * BN + wn + j * 16 + l16;
        const float bv = bias[col];
        #pragma unroll
        for (int i = 0; i < 2; ++i) {
            const int row0 = bm * BM + wm + i * 16 + quad * 4;
            #pragma unroll
            for (int r = 0; r < 4; ++r)
                out[(size_t)(row0 + r) * N + col] = acc[i][j][r] + bv;
        }
    }
}

extern "C" void kernel_launch(void* const* d_in, const int* in_sizes, int n_in,
                              void* d_out, int out_size, void* d_ws, size_t ws_size,
                              hipStream_t stream) {
    const float* x    = (const float*)d_in[0];   // (512, 2048)
    const float* w    = (const float*)d_in[1];   // (2048, 2048) = (N, K)
    const float* bias = (const float*)d_in[2];   // (2048,)
    float* out = (float*)d_out;                  // (512, 2048)

    dim3 grid(N / BN, M / BM);                   // (32, 8) = 256 blocks
    memristor_gemm<<<grid, 256, 0, stream>>>(x, w, bias, out);
}

// Round 2
// 81.887 us; speedup vs baseline: 1.1819x; 1.1819x over previous
//
#include <hip/hip_runtime.h>
#include <hip/hip_bf16.h>

// out = x @ W^T + bias (memristor constants cancel exactly; see round-0).
// M=512, N=2048, K=2048 fp32 -> bf16 MFMA, fp32 accum.
//
// Round-2 design: one 64x64 output tile per CU (grid 32x8=256 blocks),
// 512 threads = 8 waves = 2x2 spatial quadrants x 2-way K-split.
// BK=128, LDS double-buffered (1 barrier/iter), register prefetch of
// tile t+2 in flight during compute of tile t. K-split partials reduced
// through LDS in the epilogue.

typedef float  float4_t __attribute__((ext_vector_type(4)));
typedef short  short8_t __attribute__((ext_vector_type(8)));
typedef float  floatx4  __attribute__((ext_vector_type(4)));

constexpr int M = 512, N = 2048, K = 2048;
constexpr int BM = 64, BN = 64, BK = 128;
constexpr int LDK = BK + 8;           // 136 bf16 elems = 272B row stride (16B-aligned rows)
constexpr int NT  = K / BK;           // 16 k-tiles

__global__ __launch_bounds__(512)
void memristor_gemm(const float* __restrict__ x, const float* __restrict__ w,
                    const float* __restrict__ bias, float* __restrict__ out)
{
    __shared__ __hip_bfloat16 As[2][BM][LDK];   // 2 x 17408 B
    __shared__ __hip_bfloat16 Bs[2][BN][LDK];

    const int tid  = threadIdx.x;
    const int bn   = blockIdx.x, bm = blockIdx.y;
    const int lane = tid & 63;
    const int wave = tid >> 6;        // 0..7
    const int wsp  = wave & 3;        // spatial quadrant (2x2 of 32x32)
    const int kp   = wave >> 2;       // k-half: handles kk in [kp*64, kp*64+64)
    const int wm   = (wsp >> 1) * 32;
    const int wn   = (wsp & 1) * 32;
    const int l16  = lane & 15;
    const int quad = lane >> 4;

    // staging map: 64 rows x 32 float4 per matrix per k-tile; 512 thr x 4 rounds
    const int srow = tid >> 5;        // 0..15 (round r covers rows r*16+srow)
    const int sc4  = tid & 31;        // float4 index within row

    const float* xp = x + (size_t)(bm * BM + srow) * K + sc4 * 4;
    const float* wp = w + (size_t)(bn * BN + srow) * K + sc4 * 4;

    floatx4 acc[2][2];
    #pragma unroll
    for (int i = 0; i < 2; ++i)
        #pragma unroll
        for (int j = 0; j < 2; ++j)
            acc[i][j] = (floatx4){0.f, 0.f, 0.f, 0.f};

    float4_t va[4], vb[4];            // prefetch registers (one k-tile of A+B rows)

    auto load_tile = [&](int t) {
        #pragma unroll
        for (int r = 0; r < 4; ++r) {
            va[r] = *(const float4_t*)(xp + (size_t)r * 16 * K + t * BK);
            vb[r] = *(const float4_t*)(wp + (size_t)r * 16 * K + t * BK);
        }
    };

    auto stage = [&](int buf) {
        #pragma unroll
        for (int r = 0; r < 4; ++r) {
            const int row = r * 16 + srow;
            union { __hip_bfloat16 h[4]; unsigned long long u; } ua, ub;
            ua.h[0] = __float2bfloat16(va[r].x);
            ua.h[1] = __float2bfloat16(va[r].y);
            ua.h[2] = __float2bfloat16(va[r].z);
            ua.h[3] = __float2bfloat16(va[r].w);
            ub.h[0] = __float2bfloat16(vb[r].x);
            ub.h[1] = __float2bfloat16(vb[r].y);
            ub.h[2] = __float2bfloat16(vb[r].z);
            ub.h[3] = __float2bfloat16(vb[r].w);
            *(unsigned long long*)&As[buf][row][sc4 * 4] = ua.u;   // ds_write_b64
            *(unsigned long long*)&Bs[buf][row][sc4 * 4] = ub.u;
        }
    };

    auto compute = [&](int buf) {
        #pragma unroll
        for (int s = 0; s < 2; ++s) {
            const int kb = kp * 64 + s * 32 + quad * 8;
            short8_t af[2], bf[2];
            af[0] = *(const short8_t*)&As[buf][wm + l16][kb];
            af[1] = *(const short8_t*)&As[buf][wm + 16 + l16][kb];
            bf[0] = *(const short8_t*)&Bs[buf][wn + l16][kb];
            bf[1] = *(const short8_t*)&Bs[buf][wn + 16 + l16][kb];
            #pragma unroll
            for (int i = 0; i < 2; ++i)
                #pragma unroll
                for (int j = 0; j < 2; ++j)
                    acc[i][j] = __builtin_amdgcn_mfma_f32_16x16x32_bf16(
                        af[i], bf[j], acc[i][j], 0, 0, 0);
        }
    };

    // --- pipelined main loop: dbuf LDS + register prefetch ---
    load_tile(0);
    stage(0);
    load_tile(1);                     // in flight across the barrier
    __syncthreads();

    for (int t = 0; t < NT; ++t) {
        const int cur = t & 1;
        compute(cur);                 // ds_reads of buf cur; no vmcnt dependence
        if (t + 1 < NT) {
            stage(cur ^ 1);           // waits tile t+1 loads, writes other buffer
            if (t + 2 < NT) load_tile(t + 2);
        }
        __syncthreads();
    }

    // --- epilogue: 2-way K-split reduction through LDS (reuse As memory) ---
    // scratch layout: [quadrant 4][col 32][row 36 floats] (transposed so the
    // 4 accumulator rows per lane are one contiguous 16B float4)
    float* scrb = (float*)&As[0][0][0];        // 4*32*36*4 = 18432 B < As
    if (kp == 1) {
        #pragma unroll
        for (int i = 0; i < 2; ++i)
            #pragma unroll
            for (int j = 0; j < 2; ++j) {
                float* p = scrb + ((wsp * 32 + j * 16 + l16) * 36 + i * 16 + quad * 4);
                *(floatx4*)p = acc[i][j];
            }
    }
    __syncthreads();
    if (kp == 0) {
        #pragma unroll
        for (int j = 0; j < 2; ++j) {
            const int col = bn * BN + wn + j * 16 + l16;
            const float bv = bias[col];
            #pragma unroll
            for (int i = 0; i < 2; ++i) {
                const floatx4 part = *(const floatx4*)(
                    scrb + ((wsp * 32 + j * 16 + l16) * 36 + i * 16 + quad * 4));
                const int row0 = bm * BM + wm + i * 16 + quad * 4;
                #pragma unroll
                for (int r = 0; r < 4; ++r)
                    out[(size_t)(row0 + r) * N + col] = acc[i][j][r] + part[r] + bv;
            }
        }
    }
}

extern "C" void kernel_launch(void* const* d_in, const int* in_sizes, int n_in,
                              void* d_out, int out_size, void* d_ws, size_t ws_size,
                              hipStream_t stream) {
    const float* x    = (const float*)d_in[0];   // (512, 2048)
    const float* w    = (const float*)d_in[1];   // (2048, 2048) = (N, K)
    const float* bias = (const float*)d_in[2];   // (2048,)
    float* out = (float*)d_out;                  // (512, 2048)

    dim3 grid(N / BN, M / BM);                   // (32, 8) = 256 blocks, 1 per CU
    memristor_gemm<<<grid, 512, 0, stream>>>(x, w, bias, out);
}